// Round 15
// baseline (597.644 us; speedup 1.0000x reference)
//
#include <hip/hip_runtime.h>

#define NT 512
#define SEQ_LEN 8192

static __device__ __forceinline__ float2 f2(float x, float y){ return make_float2(x,y); }
static __device__ __forceinline__ float2 cadd(float2 a, float2 b){ return f2(a.x+b.x, a.y+b.y); }
static __device__ __forceinline__ float2 csub(float2 a, float2 b){ return f2(a.x-b.x, a.y-b.y); }
static __device__ __forceinline__ float2 cmul(float2 a, float2 b){ return f2(a.x*b.x-a.y*b.y, a.x*b.y+a.y*b.x); }
static __device__ __forceinline__ float2 cmulc(float2 a, float2 b){ return f2(a.x*b.x+a.y*b.y, a.y*b.x-a.x*b.y); } // a*conj(b)
static __device__ __forceinline__ float2 mul_mi(float2 a){ return f2(a.y, -a.x); }  // a * (-i)
static __device__ __forceinline__ float2 mul_pi(float2 a){ return f2(-a.y, a.x); }  // a * (+i)
static __device__ __forceinline__ int swz(int e){ return e ^ ((e>>4)&15) ^ ((e>>8)&15); }
static __device__ __forceinline__ int rev13(int v){ return (int)(__brev((unsigned)v) >> 19); }

// ---------------- MLP: h3[j][16] = sin-MLP(z[j]) ----------------
__global__ void hyena_mlp(const float* __restrict__ z,
                          const float* __restrict__ W1, const float* __restrict__ b1,
                          const float* __restrict__ W2, const float* __restrict__ b2,
                          const float* __restrict__ W3, const float* __restrict__ b3,
                          const float* __restrict__ freq,
                          float* __restrict__ h3) {
    int j = blockIdx.x * blockDim.x + threadIdx.x;
    if (j >= SEQ_LEN) return;
    float z0 = z[3*j+0], z1 = z[3*j+1], z2 = z[3*j+2];
    float ha[16], hb[16];
#pragma unroll
    for (int o = 0; o < 16; ++o) {
        float acc = b1[o] + z0*W1[o] + z1*W1[16+o] + z2*W1[32+o];
        ha[o] = sinf(freq[o] * acc);
    }
#pragma unroll
    for (int p = 0; p < 16; ++p) {
        float acc = b2[p];
#pragma unroll
        for (int o = 0; o < 16; ++o) acc += ha[o] * W2[o*16+p];
        hb[p] = sinf(freq[p] * acc);
    }
#pragma unroll
    for (int q = 0; q < 16; ++q) {
        float acc = b3[q];
#pragma unroll
        for (int o = 0; o < 16; ++o) acc += hb[o] * W3[o*16+q];
        h3[j*16+q] = sinf(freq[q] * acc);
    }
}

// ------ radix-16 butterflies (kspec only, validated) ------
static __device__ __forceinline__ void dif4(float2 r[16], float2 wd){
    const float2 c1 = f2(0.9238795325112867f,-0.3826834323650898f);
    const float2 c2 = f2(0.7071067811865476f,-0.7071067811865476f);
    const float2 c3 = f2(0.3826834323650898f,-0.9238795325112867f);
    float2 wc = cmul(wd,wd), wb = cmul(wc,wc), wa = cmul(wb,wb);
    float2 t0 = wd, t1 = cmul(wd,c1), t2 = cmul(wd,c2), t3 = cmul(wd,c3);
    float2 u0 = wc, u1 = cmul(wc,c2);
    { float2 u=r[0], v=r[8];  r[0]=cadd(u,v); r[8] =cmul(csub(u,v), t0); }
    { float2 u=r[1], v=r[9];  r[1]=cadd(u,v); r[9] =cmul(csub(u,v), t1); }
    { float2 u=r[2], v=r[10]; r[2]=cadd(u,v); r[10]=cmul(csub(u,v), t2); }
    { float2 u=r[3], v=r[11]; r[3]=cadd(u,v); r[11]=cmul(csub(u,v), t3); }
    { float2 u=r[4], v=r[12]; r[4]=cadd(u,v); r[12]=mul_mi(cmul(csub(u,v), t0)); }
    { float2 u=r[5], v=r[13]; r[5]=cadd(u,v); r[13]=mul_mi(cmul(csub(u,v), t1)); }
    { float2 u=r[6], v=r[14]; r[6]=cadd(u,v); r[14]=mul_mi(cmul(csub(u,v), t2)); }
    { float2 u=r[7], v=r[15]; r[7]=cadd(u,v); r[15]=mul_mi(cmul(csub(u,v), t3)); }
#pragma unroll
    for (int b = 0; b < 16; b += 8) {
        { float2 u=r[b+0], v=r[b+4]; r[b+0]=cadd(u,v); r[b+4]=cmul(csub(u,v), u0); }
        { float2 u=r[b+1], v=r[b+5]; r[b+1]=cadd(u,v); r[b+5]=cmul(csub(u,v), u1); }
        { float2 u=r[b+2], v=r[b+6]; r[b+2]=cadd(u,v); r[b+6]=mul_mi(cmul(csub(u,v), u0)); }
        { float2 u=r[b+3], v=r[b+7]; r[b+3]=cadd(u,v); r[b+7]=mul_mi(cmul(csub(u,v), u1)); }
    }
#pragma unroll
    for (int b = 0; b < 16; b += 4) {
        { float2 u=r[b+0], v=r[b+2]; r[b+0]=cadd(u,v); r[b+2]=cmul(csub(u,v), wb); }
        { float2 u=r[b+1], v=r[b+3]; r[b+1]=cadd(u,v); r[b+3]=mul_mi(cmul(csub(u,v), wb)); }
    }
#pragma unroll
    for (int b = 0; b < 16; b += 2) { float2 u=r[b], v=r[b+1]; r[b]=cadd(u,v); r[b+1]=cmul(csub(u,v), wa); }
}

// ------ radix-8 butterflies (validated rounds 9-14) ------
static __device__ __forceinline__ void dif3(float2 r[8], float2 wd){
    const float2 c2 = f2(0.7071067811865476f,-0.7071067811865476f);
    float2 wd2 = cmul(wd,wd), wd4 = cmul(wd2,wd2);
    float2 wc2 = cmul(wd,c2);
    { float2 u=r[0], v=r[4]; r[0]=cadd(u,v); r[4]=cmul(csub(u,v), wd); }
    { float2 u=r[1], v=r[5]; r[1]=cadd(u,v); r[5]=cmul(csub(u,v), wc2); }
    { float2 u=r[2], v=r[6]; r[2]=cadd(u,v); r[6]=mul_mi(cmul(csub(u,v), wd)); }
    { float2 u=r[3], v=r[7]; r[3]=cadd(u,v); r[7]=mul_mi(cmul(csub(u,v), wc2)); }
    { float2 u=r[0], v=r[2]; r[0]=cadd(u,v); r[2]=cmul(csub(u,v), wd2); }
    { float2 u=r[1], v=r[3]; r[1]=cadd(u,v); r[3]=mul_mi(cmul(csub(u,v), wd2)); }
    { float2 u=r[4], v=r[6]; r[4]=cadd(u,v); r[6]=cmul(csub(u,v), wd2); }
    { float2 u=r[5], v=r[7]; r[5]=cadd(u,v); r[7]=mul_mi(cmul(csub(u,v), wd2)); }
    { float2 u=r[0], v=r[1]; r[0]=cadd(u,v); r[1]=cmul(csub(u,v), wd4); }
    { float2 u=r[2], v=r[3]; r[2]=cadd(u,v); r[3]=cmul(csub(u,v), wd4); }
    { float2 u=r[4], v=r[5]; r[4]=cadd(u,v); r[5]=cmul(csub(u,v), wd4); }
    { float2 u=r[6], v=r[7]; r[6]=cadd(u,v); r[7]=cmul(csub(u,v), wd4); }
}
static __device__ __forceinline__ void dit3(float2 r[8], float2 wd){
    const float2 c2 = f2(0.7071067811865476f,-0.7071067811865476f);
    float2 wd2 = cmul(wd,wd), wd4 = cmul(wd2,wd2);
    float2 wc2 = cmul(wd,c2);
    { float2 u=r[0]; float2 t=cmulc(r[1], wd4); r[0]=cadd(u,t); r[1]=csub(u,t); }
    { float2 u=r[2]; float2 t=cmulc(r[3], wd4); r[2]=cadd(u,t); r[3]=csub(u,t); }
    { float2 u=r[4]; float2 t=cmulc(r[5], wd4); r[4]=cadd(u,t); r[5]=csub(u,t); }
    { float2 u=r[6]; float2 t=cmulc(r[7], wd4); r[6]=cadd(u,t); r[7]=csub(u,t); }
    { float2 u=r[0]; float2 t=cmulc(r[2], wd2);         r[0]=cadd(u,t); r[2]=csub(u,t); }
    { float2 u=r[1]; float2 t=mul_pi(cmulc(r[3], wd2)); r[1]=cadd(u,t); r[3]=csub(u,t); }
    { float2 u=r[4]; float2 t=cmulc(r[6], wd2);         r[4]=cadd(u,t); r[6]=csub(u,t); }
    { float2 u=r[5]; float2 t=mul_pi(cmulc(r[7], wd2)); r[5]=cadd(u,t); r[7]=csub(u,t); }
    { float2 u=r[0]; float2 t=cmulc(r[4], wd);          r[0]=cadd(u,t); r[4]=csub(u,t); }
    { float2 u=r[1]; float2 t=cmulc(r[5], wc2);         r[1]=cadd(u,t); r[5]=csub(u,t); }
    { float2 u=r[2]; float2 t=mul_pi(cmulc(r[6], wd));  r[2]=cadd(u,t); r[6]=csub(u,t); }
    { float2 u=r[3]; float2 t=mul_pi(cmulc(r[7], wc2)); r[3]=cadd(u,t); r[7]=csub(u,t); }
}

// aligned pair access
static __device__ __forceinline__ void readpair(const float2* cv, int p, float2& e0, float2& e1){
    int sp = swz(p);
    float4 q = *(const float4*)&cv[sp & ~1];
    float2 lo = f2(q.x,q.y), hi = f2(q.z,q.w);
    if (sp & 1) { e0 = hi; e1 = lo; } else { e0 = lo; e1 = hi; }
}
static __device__ __forceinline__ void writepair(float2* cv, int p, float2 e0, float2 e1){
    int sp = swz(p);
    float4 q;
    if (sp & 1) q = make_float4(e1.x,e1.y,e0.x,e0.y);
    else        q = make_float4(e0.x,e0.y,e1.x,e1.y);
    *(float4*)&cv[sp & ~1] = q;
}

static __device__ __forceinline__ float2 getw(const float2* T1, const float2* T2, int k){
    return cmul(T1[k>>6], T2[k&63]);   // e^{-i pi k / 8192}
}
static __device__ __forceinline__ float4 kpack(float2 Ck, float2 Cm, float2 w, float bds){
    const float s = 1.0f/16384.0f;
    float2 A  = f2(0.5f*(Ck.x+Cm.x), 0.5f*(Ck.y-Cm.y));
    float2 Bc = f2(0.5f*(Ck.x-Cm.x), 0.5f*(Ck.y+Cm.y));
    float2 B  = f2(Bc.y, -Bc.x);
    float2 wB = cmul(w, B);
    return make_float4((A.x+wB.x)*s + bds, (A.y+wB.y)*s,
                       (A.x-wB.x)*s + bds, -((A.y-wB.y)*s));
}
static __device__ __forceinline__ void pwmul(float2 Ck, float2 Cm, float4 Kp, float2 w,
                                             float2& Dk, float2& Dm){
    float2 A  = f2(0.5f*(Ck.x+Cm.x), 0.5f*(Ck.y-Cm.y));
    float2 Bc = f2(0.5f*(Ck.x-Cm.x), 0.5f*(Ck.y+Cm.y));
    float2 B  = f2(Bc.y, -Bc.x);
    float2 wB = cmul(w, B);
    float2 Xk = f2(A.x+wB.x, A.y+wB.y);
    float2 Xm = f2(A.x-wB.x, -(A.y-wB.y));
    float2 Yk = cmul(Xk, f2(Kp.x,Kp.y));
    float2 Ym = cmul(Xm, f2(Kp.z,Kp.w));
    float2 A2 = f2(Yk.x+Ym.x, Yk.y-Ym.y);
    float2 Bt = f2(Yk.x-Ym.x, Yk.y+Ym.y);
    float2 B2 = cmulc(Bt, w);
    Dk = f2(A2.x - B2.y, A2.y + B2.x);
    Dm = f2(A2.x + B2.y, B2.x - A2.y);
}

// ====== kernel 1: K spectrum -> global A[d][4096] (validated rounds 11-14) ======
#define SMEMK_BYTES (8832 * 8)
__global__ __launch_bounds__(NT)
void hyena_kspec(const float* __restrict__ h3g, const float* __restrict__ Wout,
                 const float* __restrict__ bias, float4* __restrict__ A) {
    extern __shared__ float2 smem[];
    float2* cv  = smem;
    float2* tab = cv + 8192;
    float2* T1  = tab + 512;
    float2* T2  = T1 + 64;
    const int t = threadIdx.x;
    const int d = blockIdx.x;
    const float PI = 3.14159265358979323846f;

    { float s_,c_; sincosf((PI/4096.0f)*(float)t, &s_, &c_); tab[t] = f2(c_, -s_); }
    if (t < 64)       { float s_,c_; sincosf((PI/128.0f)*(float)t, &s_,&c_); T1[t] = f2(c_,-s_); }
    else if (t < 128) { int l=t-64; float s_,c_; sincosf((PI/8192.0f)*(float)l,&s_,&c_); T2[l] = f2(c_,-s_); }
    __syncthreads();

    const float2 wd1 = tab[t];
    const float2 wd2 = tab[(t&31)<<4];
    const float2 wd3 = tab[(t&1)<<8];
    const int b2 = ((t>>5)<<9) | (t&31);
    const int b3 = ((t>>1)<<5) | (t&1);

    const float dmin = -3.0701134573253941f;
    const float dmax = -15.350567286626971f;
    const float absd = fabsf(dmin + (dmax - dmin) * ((float)d * (1.0f/1023.0f)));
    const float bds = bias[d] * (1.0f/16384.0f);

    float2 r[16];
    {
        float wcol[16];
#pragma unroll
        for (int o = 0; o < 16; ++o) wcol[o] = Wout[o*1024 + d];
#pragma unroll
        for (int k = 0; k < 8; ++k) {
            int e = t + 512*k;
            const float4* h4 = (const float4*)(h3g + (size_t)(2*e)*16);
            float a0 = 0.f, a1 = 0.f;
#pragma unroll
            for (int v4 = 0; v4 < 4; ++v4) {
                float4 q0 = h4[v4], q1 = h4[4+v4];
                a0 += q0.x*wcol[4*v4] + q0.y*wcol[4*v4+1] + q0.z*wcol[4*v4+2] + q0.w*wcol[4*v4+3];
                a1 += q1.x*wcol[4*v4] + q1.y*wcol[4*v4+1] + q1.z*wcol[4*v4+2] + q1.w*wcol[4*v4+3];
            }
            float ta = (float)(2*e)   * (1.0f/8191.0f);
            float tb = (float)(2*e+1) * (1.0f/8191.0f);
            r[k] = f2(a0 * __expf(-ta*absd), a1 * __expf(-tb*absd));
        }
    }
#pragma unroll
    for (int k = 8; k < 16; ++k) r[k] = f2(0.f, 0.f);

    dif4(r, wd1);
#pragma unroll
    for (int k = 0; k < 16; ++k) cv[swz(t + 512*k)] = r[k];
    __syncthreads();
#pragma unroll
    for (int k = 0; k < 16; ++k) r[k] = cv[swz(b2 + 32*k)];
    dif4(r, wd2);
#pragma unroll
    for (int k = 0; k < 16; ++k) cv[swz(b2 + 32*k)] = r[k];
    __syncthreads();
#pragma unroll
    for (int k = 0; k < 16; ++k) r[k] = cv[swz(b3 + 2*k)];
    dif4(r, wd3);
#pragma unroll
    for (int k = 0; k < 16; ++k) cv[swz(b3 + 2*k)] = r[k];
    __syncthreads();

    float4* Ad = A + (size_t)d * 4096;
#pragma unroll 1
    for (int q = 0; q < 4; ++q) {
        int f = t + 512*q;
        if (f == 0) {
            float2 a0,a1; readpair(cv, 0, a0, a1);
            float2 C0 = cadd(a0,a1), C4 = csub(a0,a1);
            const float s = 1.0f/16384.0f;
            Ad[0] = make_float4((C0.x+C0.y)*s + bds, (C0.x-C0.y)*s + bds, C4.x*s + bds, -C4.y*s);
        } else {
            int g = 4096 - f;
            float2 a0,a1,b0,b1;
            readpair(cv, rev13(f), a0, a1);
            readpair(cv, rev13(g), b0, b1);
            float2 Cf=cadd(a0,a1), Cf4=csub(a0,a1), Cg=cadd(b0,b1), Cg4=csub(b0,b1);
            Ad[f] = kpack(Cf, Cg4, getw(T1,T2,f), bds);
            Ad[g] = kpack(Cg, Cf4, getw(T1,T2,g), bds);
        }
    }
    if (t == 0) {
        float2 b0,b1; readpair(cv, 2, b0, b1);   // rev13(2048) = 2
        Ad[2048] = kpack(cadd(b0,b1), csub(b0,b1), getw(T1,T2,2048), bds);
    }
}

// ====== conv8: NT=1024 radix-8, single cv, K transient from global ======
// LDS: cv 8192 | tab 1024 | T1 64 | T2 64 = 9344 f2 = 74752 B.
// 16 waves/CU = 4 waves/SIMD (double all previous convs' latency hiding).
// Anti-spill: no K build, no persistent K, r[8] only -> peak live ~50 regs,
// fits the 64-VGPR budget the compiler assigns NT=1024 blocks.
#define SMEM8_BYTES (9344 * 8)
__global__ __launch_bounds__(1024, 1)
void hyena_conv8(const float4* __restrict__ A,
                 const float* __restrict__ x, float* __restrict__ out) {
    extern __shared__ float2 smem[];
    float2* cv  = smem;          // 8192
    float2* tab = cv + 8192;     // 1024
    float2* T1  = tab + 1024;    // 64
    float2* T2  = T1 + 64;       // 64
    const int t = threadIdx.x;
    const int d = blockIdx.x;
    const float PI = 3.14159265358979323846f;

    { float s_,c_; sincosf((PI/4096.0f)*(float)t, &s_, &c_); tab[t] = f2(c_, -s_); }
    if (t < 64)       { float s_,c_; sincosf((PI/128.0f)*(float)t, &s_,&c_); T1[t] = f2(c_,-s_); }
    else if (t < 128) { int l=t-64; float s_,c_; sincosf((PI/8192.0f)*(float)l,&s_,&c_); T2[l] = f2(c_,-s_); }
    __syncthreads();

    // pass A: stages 12..10, elements t + 1024k, wd = W_8192^t
    // pass B: stages  9..7,  base bB, stride 128, wd = W_1024^(t&127)
    // pass C: stages  6..4,  base bC, stride 16,  wd = W_128^(t&15)
    // pass D: stages  3..1,  base bD, stride 2,   wd = W_16^(t&1)
    const float2 wdA = tab[t];
    const float2 wdB = tab[(t&127)<<3];
    const float2 wdC = tab[(t&15)<<6];
    const float2 wdD = tab[(t&1)<<9];
    const int bB = ((t>>7)<<10) | (t&127);
    const int bC = ((t>>4)<<7)  | (t&15);
    const int bD = ((t>>1)<<4)  | (t&1);
    const float4* Ad = A + (size_t)d * 4096;

    float2 r[8];
#pragma unroll 1
    for (int b = 0; b < 4; ++b) {
        const float2* xr = (const float2*)(x + ((size_t)b*1024 + d)*SEQ_LEN);
        float2* yr = (float2*)(out + ((size_t)b*1024 + d)*SEQ_LEN);

        // F1: pass A from global
#pragma unroll
        for (int k = 0; k < 4; ++k) r[k] = xr[t + 1024*k];
#pragma unroll
        for (int k = 4; k < 8; ++k) r[k] = f2(0.f,0.f);
        dif3(r, wdA);
#pragma unroll
        for (int k = 0; k < 8; ++k) cv[swz(t + 1024*k)] = r[k];
        __syncthreads();
        // F2: pass B
#pragma unroll
        for (int k = 0; k < 8; ++k) r[k] = cv[swz(bB + 128*k)];
        dif3(r, wdB);
#pragma unroll
        for (int k = 0; k < 8; ++k) cv[swz(bB + 128*k)] = r[k];
        __syncthreads();
        // F3: pass C
#pragma unroll
        for (int k = 0; k < 8; ++k) r[k] = cv[swz(bC + 16*k)];
        dif3(r, wdC);
#pragma unroll
        for (int k = 0; k < 8; ++k) cv[swz(bC + 16*k)] = r[k];
        __syncthreads();
        // F4: pass D
#pragma unroll
        for (int k = 0; k < 8; ++k) r[k] = cv[swz(bD + 2*k)];
        dif3(r, wdD);
#pragma unroll
        for (int k = 0; k < 8; ++k) cv[swz(bD + 2*k)] = r[k];
        __syncthreads();

        // FUSED: fwd stage 0 + unpack*K + repack + inv stage 0 (K transient per q)
#pragma unroll 1
        for (int q = 0; q < 2; ++q) {
            int f = t + 1024*q;
            float4 Kpa = Ad[f];
            float4 Kpb = Ad[(f == 0) ? 2048 : (4096 - f)];
            if (f == 0) {
                float2 a0,a1; readpair(cv, 0, a0, a1);
                float2 C0 = cadd(a0,a1), C4 = csub(a0,a1);
                float Y0 = (C0.x+C0.y) * Kpa.x, YN = (C0.x-C0.y) * Kpa.y;
                float2 D0 = f2(Y0+YN, Y0-YN);
                float2 Y4 = cmul(f2(C4.x,-C4.y), f2(Kpa.z, Kpa.w));
                float2 D4 = f2(2.f*Y4.x, -2.f*Y4.y);
                writepair(cv, 0, cadd(D0,D4), csub(D0,D4));
                // f = 2048 self-paired quad at positions (2,3)
                float2 q0,q1; readpair(cv, 2, q0, q1);
                float2 Ck=cadd(q0,q1), Cm=csub(q0,q1), Dk, Dm;
                pwmul(Ck, Cm, Kpb, getw(T1,T2,2048), Dk, Dm);
                writepair(cv, 2, cadd(Dk,Dm), csub(Dk,Dm));
            } else {
                int g = 4096 - f;
                int p1 = rev13(f), p2 = rev13(g);
                float2 a0,a1,b0,b1;
                readpair(cv, p1, a0, a1);
                readpair(cv, p2, b0, b1);
                float2 Cf=cadd(a0,a1), Cf4=csub(a0,a1), Cg=cadd(b0,b1), Cg4=csub(b0,b1);
                float2 Df,Dg4,Dg,Df4;
                pwmul(Cf, Cg4, Kpa, getw(T1,T2,f), Df, Dg4);
                pwmul(Cg, Cf4, Kpb, getw(T1,T2,g), Dg, Df4);
                writepair(cv, p1, cadd(Df,Df4), csub(Df,Df4));
                writepair(cv, p2, cadd(Dg,Dg4), csub(Dg,Dg4));
            }
        }
        __syncthreads();

        // I4: pass D' (stages 1..3)
#pragma unroll
        for (int k = 0; k < 8; ++k) r[k] = cv[swz(bD + 2*k)];
        dit3(r, wdD);
#pragma unroll
        for (int k = 0; k < 8; ++k) cv[swz(bD + 2*k)] = r[k];
        __syncthreads();
        // I3: pass C' (stages 4..6)
#pragma unroll
        for (int k = 0; k < 8; ++k) r[k] = cv[swz(bC + 16*k)];
        dit3(r, wdC);
#pragma unroll
        for (int k = 0; k < 8; ++k) cv[swz(bC + 16*k)] = r[k];
        __syncthreads();
        // I2: pass B' (stages 7..9)
#pragma unroll
        for (int k = 0; k < 8; ++k) r[k] = cv[swz(bB + 128*k)];
        dit3(r, wdB);
#pragma unroll
        for (int k = 0; k < 8; ++k) cv[swz(bB + 128*k)] = r[k];
        __syncthreads();
        // I1: pass A' (stages 10..12), first half straight to global
#pragma unroll
        for (int k = 0; k < 8; ++k) r[k] = cv[swz(t + 1024*k)];
        dit3(r, wdA);
#pragma unroll
        for (int k = 0; k < 4; ++k) yr[t + 1024*k] = r[k];
        __syncthreads();
    }
}

// ====== FALLBACK: round-10 radix-8 conv (validated best standalone: 345 µs) ======
#define SMEMF_BYTES (9348 * 8)
__global__ __launch_bounds__(NT, 2)
void hyena_conv_r10(const float* __restrict__ h3g, const float* __restrict__ Wout,
                    const float* __restrict__ x, const float* __restrict__ bias,
                    float* __restrict__ out) {
    extern __shared__ float2 smem[];
    float2* cv  = smem;
    float2* tab = cv + 8192;            // 1024
    float2* T1  = tab + 1024;
    float2* T2  = T1 + 64;
    float2* Kex = T2 + 64;
    const int t = threadIdx.x;
    const int d = blockIdx.x;
    const float PI = 3.14159265358979323846f;

#pragma unroll
    for (int i = 0; i < 2; ++i) {
        int p = t + 512*i;
        float s_,c_; sincosf((PI/4096.0f)*(float)p, &s_, &c_); tab[p] = f2(c_, -s_);
    }
    if (t < 64)       { float s_,c_; sincosf((PI/128.0f)*(float)t, &s_,&c_); T1[t] = f2(c_,-s_); }
    else if (t < 128) { int l=t-64; float s_,c_; sincosf((PI/8192.0f)*(float)l,&s_,&c_); T2[l] = f2(c_,-s_); }
    __syncthreads();

    const float2 wdB = tab[(t&127)<<3];
    const float2 wdC = tab[(t&15)<<6];
    const float2 wdD = tab[(t&1)<<9];
    const float bds = bias[d] * (1.0f/16384.0f);

    float2 r[8];
#pragma unroll 1
    for (int gi = 0; gi < 2; ++gi) {
        int g = t + 512*gi;
        const float dmin = -3.0701134573253941f;
        const float dmax = -15.350567286626971f;
        const float absd = fabsf(dmin + (dmax - dmin) * ((float)d * (1.0f/1023.0f)));
#pragma unroll
        for (int k = 0; k < 4; ++k) {
            int e = g + 1024*k;
            const float4* h4 = (const float4*)(h3g + (size_t)(2*e)*16);
            float a0 = 0.f, a1 = 0.f;
#pragma unroll
            for (int v4 = 0; v4 < 4; ++v4) {
                float4 q0 = h4[v4], q1 = h4[4+v4];
                float w0 = Wout[(4*v4+0)*1024 + d], w1 = Wout[(4*v4+1)*1024 + d];
                float w2 = Wout[(4*v4+2)*1024 + d], w3 = Wout[(4*v4+3)*1024 + d];
                a0 += q0.x*w0 + q0.y*w1 + q0.z*w2 + q0.w*w3;
                a1 += q1.x*w0 + q1.y*w1 + q1.z*w2 + q1.w*w3;
            }
            float ta = (float)(2*e)   * (1.0f/8191.0f);
            float tb = (float)(2*e+1) * (1.0f/8191.0f);
            r[k] = f2(a0 * __expf(-ta*absd), a1 * __expf(-tb*absd));
        }
#pragma unroll
        for (int k = 4; k < 8; ++k) r[k] = f2(0.f, 0.f);
        dif3(r, tab[g]);
#pragma unroll
        for (int k = 0; k < 8; ++k) cv[swz(g + 1024*k)] = r[k];
    }
    __syncthreads();
#pragma unroll 1
    for (int gi = 0; gi < 2; ++gi) {
        int g = t + 512*gi; int base = ((g>>7)<<10) | (g&127);
#pragma unroll
        for (int k = 0; k < 8; ++k) r[k] = cv[swz(base + 128*k)];
        dif3(r, wdB);
#pragma unroll
        for (int k = 0; k < 8; ++k) cv[swz(base + 128*k)] = r[k];
    }
    __syncthreads();
#pragma unroll 1
    for (int gi = 0; gi < 2; ++gi) {
        int g = t + 512*gi; int base = ((g>>4)<<7) | (g&15);
#pragma unroll
        for (int k = 0; k < 8; ++k) r[k] = cv[swz(base + 16*k)];
        dif3(r, wdC);
#pragma unroll
        for (int k = 0; k < 8; ++k) cv[swz(base + 16*k)] = r[k];
    }
    __syncthreads();
#pragma unroll 1
    for (int gi = 0; gi < 2; ++gi) {
        int g = t + 512*gi; int base = ((g>>1)<<4) | (g&1);
#pragma unroll
        for (int k = 0; k < 8; ++k) r[k] = cv[swz(base + 2*k)];
        dif3(r, wdD);
#pragma unroll
        for (int k = 0; k < 8; ++k) cv[swz(base + 2*k)] = r[k];
    }
    __syncthreads();

    float4 Ka[4], Kb[4];
#pragma unroll
    for (int q = 0; q < 4; ++q) {
        int f = t + 512*q;
        if (f == 0) {
            float2 a0,a1; readpair(cv, 0, a0, a1);
            float2 C0 = cadd(a0,a1), C4 = csub(a0,a1);
            const float s = 1.0f/16384.0f;
            Ka[q] = make_float4((C0.x+C0.y)*s + bds, (C0.x-C0.y)*s + bds, C4.x*s + bds, -C4.y*s);
            Kb[q] = make_float4(0.f,0.f,0.f,0.f);
        } else {
            int g = 4096 - f;
            float2 a0,a1,b0,b1;
            readpair(cv, rev13(f), a0, a1);
            readpair(cv, rev13(g), b0, b1);
            float2 Cf=cadd(a0,a1), Cf4=csub(a0,a1), Cg=cadd(b0,b1), Cg4=csub(b0,b1);
            Ka[q] = kpack(Cf, Cg4, getw(T1,T2,f), bds);
            Kb[q] = kpack(Cg, Cf4, getw(T1,T2,g), bds);
        }
    }
    if (t == 0) {
        float2 b0,b1; readpair(cv, 2, b0, b1);
        float4 K20 = kpack(cadd(b0,b1), csub(b0,b1), getw(T1,T2,2048), bds);
        Kex[0] = f2(K20.x, K20.y);
        Kex[1] = f2(K20.z, K20.w);
    }
    __syncthreads();

#pragma unroll 1
    for (int b = 0; b < 4; ++b) {
        const float2* xr = (const float2*)(x + ((size_t)b*1024 + d)*SEQ_LEN);
        float2* yr = (float2*)(out + ((size_t)b*1024 + d)*SEQ_LEN);
#pragma unroll 1
        for (int gi = 0; gi < 2; ++gi) {
            int g = t + 512*gi;
#pragma unroll
            for (int k = 0; k < 4; ++k) r[k] = xr[g + 1024*k];
#pragma unroll
            for (int k = 4; k < 8; ++k) r[k] = f2(0.f,0.f);
            dif3(r, tab[g]);
#pragma unroll
            for (int k = 0; k < 8; ++k) cv[swz(g + 1024*k)] = r[k];
        }
        __syncthreads();
#pragma unroll 1
        for (int gi = 0; gi < 2; ++gi) {
            int g = t + 512*gi; int base = ((g>>7)<<10) | (g&127);
#pragma unroll
            for (int k = 0; k < 8; ++k) r[k] = cv[swz(base + 128*k)];
            dif3(r, wdB);
#pragma unroll
            for (int k = 0; k < 8; ++k) cv[swz(base + 128*k)] = r[k];
        }
        __syncthreads();
#pragma unroll 1
        for (int gi = 0; gi < 2; ++gi) {
            int g = t + 512*gi; int base = ((g>>4)<<7) | (g&15);
#pragma unroll
            for (int k = 0; k < 8; ++k) r[k] = cv[swz(base + 16*k)];
            dif3(r, wdC);
#pragma unroll
            for (int k = 0; k < 8; ++k) cv[swz(base + 16*k)] = r[k];
        }
        __syncthreads();
#pragma unroll 1
        for (int gi = 0; gi < 2; ++gi) {
            int g = t + 512*gi; int base = ((g>>1)<<4) | (g&1);
#pragma unroll
            for (int k = 0; k < 8; ++k) r[k] = cv[swz(base + 2*k)];
            dif3(r, wdD);
#pragma unroll
            for (int k = 0; k < 8; ++k) cv[swz(base + 2*k)] = r[k];
        }
        __syncthreads();
#pragma unroll
        for (int q = 0; q < 4; ++q) {
            int f = t + 512*q;
            if (f == 0) {
                float2 a0,a1; readpair(cv, 0, a0, a1);
                float2 C0 = cadd(a0,a1), C4 = csub(a0,a1);
                float Y0 = (C0.x+C0.y) * Ka[0].x, YN = (C0.x-C0.y) * Ka[0].y;
                float2 D0 = f2(Y0+YN, Y0-YN);
                float2 Y4 = cmul(f2(C4.x,-C4.y), f2(Ka[0].z, Ka[0].w));
                float2 D4 = f2(2.f*Y4.x, -2.f*Y4.y);
                writepair(cv, 0, cadd(D0,D4), csub(D0,D4));
            } else {
                int g = 4096 - f;
                int p1 = rev13(f), p2 = rev13(g);
                float2 a0,a1,b0,b1;
                readpair(cv, p1, a0, a1);
                readpair(cv, p2, b0, b1);
                float2 Cf=cadd(a0,a1), Cf4=csub(a0,a1), Cg=cadd(b0,b1), Cg4=csub(b0,b1);
                float2 Df,Dg4,Dg,Df4;
                pwmul(Cf, Cg4, Ka[q], getw(T1,T2,f), Df, Dg4);
                pwmul(Cg, Cf4, Kb[q], getw(T1,T2,g), Dg, Df4);
                writepair(cv, p1, cadd(Df,Df4), csub(Df,Df4));
                writepair(cv, p2, cadd(Dg,Dg4), csub(Dg,Dg4));
            }
        }
        if (t == 0) {
            float4 K20 = make_float4(Kex[0].x, Kex[0].y, Kex[1].x, Kex[1].y);
            float2 b0,b1; readpair(cv, 2, b0, b1);
            float2 Ck=cadd(b0,b1), Cm=csub(b0,b1), Dk, Dm;
            pwmul(Ck, Cm, K20, getw(T1,T2,2048), Dk, Dm);
            writepair(cv, 2, cadd(Dk,Dm), csub(Dk,Dm));
        }
        __syncthreads();
#pragma unroll 1
        for (int gi = 0; gi < 2; ++gi) {
            int g = t + 512*gi; int base = ((g>>1)<<4) | (g&1);
#pragma unroll
            for (int k = 0; k < 8; ++k) r[k] = cv[swz(base + 2*k)];
            dit3(r, wdD);
#pragma unroll
            for (int k = 0; k < 8; ++k) cv[swz(base + 2*k)] = r[k];
        }
        __syncthreads();
#pragma unroll 1
        for (int gi = 0; gi < 2; ++gi) {
            int g = t + 512*gi; int base = ((g>>4)<<7) | (g&15);
#pragma unroll
            for (int k = 0; k < 8; ++k) r[k] = cv[swz(base + 16*k)];
            dit3(r, wdC);
#pragma unroll
            for (int k = 0; k < 8; ++k) cv[swz(base + 16*k)] = r[k];
        }
        __syncthreads();
#pragma unroll 1
        for (int gi = 0; gi < 2; ++gi) {
            int g = t + 512*gi; int base = ((g>>7)<<10) | (g&127);
#pragma unroll
            for (int k = 0; k < 8; ++k) r[k] = cv[swz(base + 128*k)];
            dit3(r, wdB);
#pragma unroll
            for (int k = 0; k < 8; ++k) cv[swz(base + 128*k)] = r[k];
        }
        __syncthreads();
#pragma unroll 1
        for (int gi = 0; gi < 2; ++gi) {
            int g = t + 512*gi;
#pragma unroll
            for (int k = 0; k < 8; ++k) r[k] = cv[swz(g + 1024*k)];
            dit3(r, tab[g]);
#pragma unroll
            for (int k = 0; k < 4; ++k) yr[g + 1024*k] = r[k];
        }
        __syncthreads();
    }
}

extern "C" void kernel_launch(void* const* d_in, const int* in_sizes, int n_in,
                              void* d_out, int out_size, void* d_ws, size_t ws_size,
                              hipStream_t stream) {
    const float* x    = (const float*)d_in[0];
    const float* z    = (const float*)d_in[2];
    const float* W1   = (const float*)d_in[3];
    const float* b1   = (const float*)d_in[4];
    const float* W2   = (const float*)d_in[5];
    const float* b2   = (const float*)d_in[6];
    const float* W3   = (const float*)d_in[7];
    const float* b3   = (const float*)d_in[8];
    const float* Wout = (const float*)d_in[9];
    const float* freq = (const float*)d_in[10];
    const float* bias = (const float*)d_in[11];
    float* out = (float*)d_out;
    float* h3  = (float*)d_ws;                                   // 512 KB
    float4* A  = (float4*)((char*)d_ws + 512*1024);              // 64 MB K-spectrum

    const size_t need2 = 512*1024 + (size_t)1024*4096*16;        // 64.5 MB

    hipLaunchKernelGGL(hyena_mlp, dim3(SEQ_LEN/256), dim3(256), 0, stream,
                       z, W1, b1, W2, b2, W3, b3, freq, h3);

    static bool attr_set = false;
    if (!attr_set) {
        (void)hipFuncSetAttribute((const void*)hyena_kspec,
                                  hipFuncAttributeMaxDynamicSharedMemorySize, SMEMK_BYTES);
        (void)hipFuncSetAttribute((const void*)hyena_conv8,
                                  hipFuncAttributeMaxDynamicSharedMemorySize, SMEM8_BYTES);
        (void)hipFuncSetAttribute((const void*)hyena_conv_r10,
                                  hipFuncAttributeMaxDynamicSharedMemorySize, SMEMF_BYTES);
        attr_set = true;
    }

    if (ws_size >= need2) {
        hipLaunchKernelGGL(hyena_kspec, dim3(1024), dim3(NT), SMEMK_BYTES, stream,
                           h3, Wout, bias, A);
        hipLaunchKernelGGL(hyena_conv8, dim3(1024), dim3(1024), SMEM8_BYTES, stream,
                           A, x, out);
    } else {
        hipLaunchKernelGGL(hyena_conv_r10, dim3(1024), dim3(NT), SMEMF_BYTES, stream,
                           h3, Wout, x, bias, out);
    }
}

// Round 16
// 343.650 us; speedup vs baseline: 1.7391x; 1.7391x over previous
//
#include <hip/hip_runtime.h>

#define NT 512
#define SEQ_LEN 8192

static __device__ __forceinline__ float2 f2(float x, float y){ return make_float2(x,y); }
static __device__ __forceinline__ float2 cadd(float2 a, float2 b){ return f2(a.x+b.x, a.y+b.y); }
static __device__ __forceinline__ float2 csub(float2 a, float2 b){ return f2(a.x-b.x, a.y-b.y); }
static __device__ __forceinline__ float2 cmul(float2 a, float2 b){ return f2(a.x*b.x-a.y*b.y, a.x*b.y+a.y*b.x); }
static __device__ __forceinline__ float2 cmulc(float2 a, float2 b){ return f2(a.x*b.x+a.y*b.y, a.y*b.x-a.x*b.y); } // a*conj(b)
static __device__ __forceinline__ float2 mul_mi(float2 a){ return f2(a.y, -a.x); }  // a * (-i)
static __device__ __forceinline__ float2 mul_pi(float2 a){ return f2(-a.y, a.x); }  // a * (+i)
static __device__ __forceinline__ int swz(int e){ return e ^ ((e>>4)&15) ^ ((e>>8)&15); }
static __device__ __forceinline__ int rev13(int v){ return (int)(__brev((unsigned)v) >> 19); }

// ---------------- MLP: h3[j][16] = sin-MLP(z[j]) ----------------
__global__ void hyena_mlp(const float* __restrict__ z,
                          const float* __restrict__ W1, const float* __restrict__ b1,
                          const float* __restrict__ W2, const float* __restrict__ b2,
                          const float* __restrict__ W3, const float* __restrict__ b3,
                          const float* __restrict__ freq,
                          float* __restrict__ h3) {
    int j = blockIdx.x * blockDim.x + threadIdx.x;
    if (j >= SEQ_LEN) return;
    float z0 = z[3*j+0], z1 = z[3*j+1], z2 = z[3*j+2];
    float ha[16], hb[16];
#pragma unroll
    for (int o = 0; o < 16; ++o) {
        float acc = b1[o] + z0*W1[o] + z1*W1[16+o] + z2*W1[32+o];
        ha[o] = sinf(freq[o] * acc);
    }
#pragma unroll
    for (int p = 0; p < 16; ++p) {
        float acc = b2[p];
#pragma unroll
        for (int o = 0; o < 16; ++o) acc += ha[o] * W2[o*16+p];
        hb[p] = sinf(freq[p] * acc);
    }
#pragma unroll
    for (int q = 0; q < 16; ++q) {
        float acc = b3[q];
#pragma unroll
        for (int o = 0; o < 16; ++o) acc += hb[o] * W3[o*16+q];
        h3[j*16+q] = sinf(freq[q] * acc);
    }
}

// ------ radix-8 (3 radix-2 stages) register butterflies (validated rounds 9-15) ------
static __device__ __forceinline__ void dif3(float2 r[8], float2 wd){
    const float2 c2 = f2(0.7071067811865476f,-0.7071067811865476f);
    float2 wd2 = cmul(wd,wd), wd4 = cmul(wd2,wd2);
    float2 wc2 = cmul(wd,c2);
    { float2 u=r[0], v=r[4]; r[0]=cadd(u,v); r[4]=cmul(csub(u,v), wd); }
    { float2 u=r[1], v=r[5]; r[1]=cadd(u,v); r[5]=cmul(csub(u,v), wc2); }
    { float2 u=r[2], v=r[6]; r[2]=cadd(u,v); r[6]=mul_mi(cmul(csub(u,v), wd)); }
    { float2 u=r[3], v=r[7]; r[3]=cadd(u,v); r[7]=mul_mi(cmul(csub(u,v), wc2)); }
    { float2 u=r[0], v=r[2]; r[0]=cadd(u,v); r[2]=cmul(csub(u,v), wd2); }
    { float2 u=r[1], v=r[3]; r[1]=cadd(u,v); r[3]=mul_mi(cmul(csub(u,v), wd2)); }
    { float2 u=r[4], v=r[6]; r[4]=cadd(u,v); r[6]=cmul(csub(u,v), wd2); }
    { float2 u=r[5], v=r[7]; r[5]=cadd(u,v); r[7]=mul_mi(cmul(csub(u,v), wd2)); }
    { float2 u=r[0], v=r[1]; r[0]=cadd(u,v); r[1]=cmul(csub(u,v), wd4); }
    { float2 u=r[2], v=r[3]; r[2]=cadd(u,v); r[3]=cmul(csub(u,v), wd4); }
    { float2 u=r[4], v=r[5]; r[4]=cadd(u,v); r[5]=cmul(csub(u,v), wd4); }
    { float2 u=r[6], v=r[7]; r[6]=cadd(u,v); r[7]=cmul(csub(u,v), wd4); }
}
static __device__ __forceinline__ void dit3(float2 r[8], float2 wd){
    const float2 c2 = f2(0.7071067811865476f,-0.7071067811865476f);
    float2 wd2 = cmul(wd,wd), wd4 = cmul(wd2,wd2);
    float2 wc2 = cmul(wd,c2);
    { float2 u=r[0]; float2 t=cmulc(r[1], wd4); r[0]=cadd(u,t); r[1]=csub(u,t); }
    { float2 u=r[2]; float2 t=cmulc(r[3], wd4); r[2]=cadd(u,t); r[3]=csub(u,t); }
    { float2 u=r[4]; float2 t=cmulc(r[5], wd4); r[4]=cadd(u,t); r[5]=csub(u,t); }
    { float2 u=r[6]; float2 t=cmulc(r[7], wd4); r[6]=cadd(u,t); r[7]=csub(u,t); }
    { float2 u=r[0]; float2 t=cmulc(r[2], wd2);         r[0]=cadd(u,t); r[2]=csub(u,t); }
    { float2 u=r[1]; float2 t=mul_pi(cmulc(r[3], wd2)); r[1]=cadd(u,t); r[3]=csub(u,t); }
    { float2 u=r[4]; float2 t=cmulc(r[6], wd2);         r[4]=cadd(u,t); r[6]=csub(u,t); }
    { float2 u=r[5]; float2 t=mul_pi(cmulc(r[7], wd2)); r[5]=cadd(u,t); r[7]=csub(u,t); }
    { float2 u=r[0]; float2 t=cmulc(r[4], wd);          r[0]=cadd(u,t); r[4]=csub(u,t); }
    { float2 u=r[1]; float2 t=cmulc(r[5], wc2);         r[1]=cadd(u,t); r[5]=csub(u,t); }
    { float2 u=r[2]; float2 t=mul_pi(cmulc(r[6], wd));  r[2]=cadd(u,t); r[6]=csub(u,t); }
    { float2 u=r[3]; float2 t=mul_pi(cmulc(r[7], wc2)); r[3]=cadd(u,t); r[7]=csub(u,t); }
}

// aligned pair access (positions p even; swz may flip parity, so select)
static __device__ __forceinline__ void readpair(const float2* cv, int p, float2& e0, float2& e1){
    int sp = swz(p);
    float4 q = *(const float4*)&cv[sp & ~1];
    float2 lo = f2(q.x,q.y), hi = f2(q.z,q.w);
    if (sp & 1) { e0 = hi; e1 = lo; } else { e0 = lo; e1 = hi; }
}
static __device__ __forceinline__ void writepair(float2* cv, int p, float2 e0, float2 e1){
    int sp = swz(p);
    float4 q;
    if (sp & 1) q = make_float4(e1.x,e1.y,e0.x,e0.y);
    else        q = make_float4(e0.x,e0.y,e1.x,e1.y);
    *(float4*)&cv[sp & ~1] = q;
}

static __device__ __forceinline__ float2 getw(const float2* T1, const float2* T2, int k){
    return cmul(T1[k>>6], T2[k&63]);   // e^{-i pi k / 8192}
}
static __device__ __forceinline__ float4 kpack(float2 Ck, float2 Cm, float2 w, float bds){
    const float s = 1.0f/16384.0f;
    float2 A  = f2(0.5f*(Ck.x+Cm.x), 0.5f*(Ck.y-Cm.y));
    float2 Bc = f2(0.5f*(Ck.x-Cm.x), 0.5f*(Ck.y+Cm.y));
    float2 B  = f2(Bc.y, -Bc.x);
    float2 wB = cmul(w, B);
    return make_float4((A.x+wB.x)*s + bds, (A.y+wB.y)*s,
                       (A.x-wB.x)*s + bds, -((A.y-wB.y)*s));
}
static __device__ __forceinline__ void pwmul(float2 Ck, float2 Cm, float4 Kp, float2 w,
                                             float2& Dk, float2& Dm){
    float2 A  = f2(0.5f*(Ck.x+Cm.x), 0.5f*(Ck.y-Cm.y));
    float2 Bc = f2(0.5f*(Ck.x-Cm.x), 0.5f*(Ck.y+Cm.y));
    float2 B  = f2(Bc.y, -Bc.x);
    float2 wB = cmul(w, B);
    float2 Xk = f2(A.x+wB.x, A.y+wB.y);
    float2 Xm = f2(A.x-wB.x, -(A.y-wB.y));
    float2 Yk = cmul(Xk, f2(Kp.x,Kp.y));
    float2 Ym = cmul(Xm, f2(Kp.z,Kp.w));
    float2 A2 = f2(Yk.x+Ym.x, Yk.y-Ym.y);
    float2 Bt = f2(Yk.x-Ym.x, Yk.y+Ym.y);
    float2 B2 = cmulc(Bt, w);
    Dk = f2(A2.x - B2.y, A2.y + B2.x);
    Dm = f2(A2.x + B2.y, B2.x - A2.y);
}

// LDS (f2): cv 8192 | tab 1024 | T1 64 | T2 64 | Kex 2 (+2 pad) = 9348 f2 = 74784 B
// Round-10 configuration: zero scratch (FETCH ~83 MB = compulsory), VGPR 128,
// VALUBusy ~58%. Validated best total (356.9 µs). Rounds 11-15 established that
// every higher-ILP/occupancy variant re-trips the toolchain's hard VGPR budget
// (128 @ NT=512, 64 @ NT=1024) or gains nothing (2 blocks/CU never co-schedule).
#define SMEM_BYTES (9348 * 8)

__global__ __launch_bounds__(NT, 2)
void hyena_conv(const float* __restrict__ h3g, const float* __restrict__ Wout,
                const float* __restrict__ x, const float* __restrict__ bias,
                float* __restrict__ out) {
    extern __shared__ float2 smem[];
    float2* cv  = smem;
    float2* tab = cv + 8192;            // 1024: e^{-i pi p/4096}
    float2* T1  = tab + 1024;           // 64:  e^{-i pi h/128}
    float2* T2  = T1 + 64;              // 64:  e^{-i pi l/8192}
    float2* Kex = T2 + 64;              // 2:   K-pack for f=2048 (lane-0 only)
    const int t = threadIdx.x;
    const int d = blockIdx.x;
    const float PI = 3.14159265358979323846f;

#pragma unroll
    for (int i = 0; i < 2; ++i) {
        int p = t + 512*i;
        float s_,c_; sincosf((PI/4096.0f)*(float)p, &s_, &c_); tab[p] = f2(c_, -s_);
    }
    if (t < 64)       { float s_,c_; sincosf((PI/128.0f)*(float)t, &s_,&c_); T1[t] = f2(c_,-s_); }
    else if (t < 128) { int l=t-64; float s_,c_; sincosf((PI/8192.0f)*(float)l,&s_,&c_); T2[l] = f2(c_,-s_); }
    __syncthreads();

    const float2 wdB = tab[(t&127)<<3];   // W_1024^(g&127)
    const float2 wdC = tab[(t&15)<<6];    // W_128^(g&15)
    const float2 wdD = tab[(t&1)<<9];     // W_16^(g&1)
    const float bds = bias[d] * (1.0f/16384.0f);

    float2 r[8];
    // ---- filter: pass A (stages 12..10) from source, 2 groups/thread ----
#pragma unroll 1
    for (int gi = 0; gi < 2; ++gi) {
        int g = t + 512*gi;
        const float dmin = -3.0701134573253941f;   // log(0.01)/1.5
        const float dmax = -15.350567286626971f;   // log(0.01)/0.3
        const float absd = fabsf(dmin + (dmax - dmin) * ((float)d * (1.0f/1023.0f)));
#pragma unroll
        for (int k = 0; k < 4; ++k) {
            int e = g + 1024*k;
            const float4* h4 = (const float4*)(h3g + (size_t)(2*e)*16);
            float a0 = 0.f, a1 = 0.f;
#pragma unroll
            for (int v4 = 0; v4 < 4; ++v4) {
                float4 q0 = h4[v4], q1 = h4[4+v4];
                float w0 = Wout[(4*v4+0)*1024 + d], w1 = Wout[(4*v4+1)*1024 + d];
                float w2 = Wout[(4*v4+2)*1024 + d], w3 = Wout[(4*v4+3)*1024 + d];
                a0 += q0.x*w0 + q0.y*w1 + q0.z*w2 + q0.w*w3;
                a1 += q1.x*w0 + q1.y*w1 + q1.z*w2 + q1.w*w3;
            }
            float ta = (float)(2*e)   * (1.0f/8191.0f);
            float tb = (float)(2*e+1) * (1.0f/8191.0f);
            r[k] = f2(a0 * __expf(-ta*absd), a1 * __expf(-tb*absd));
        }
#pragma unroll
        for (int k = 4; k < 8; ++k) r[k] = f2(0.f, 0.f);
        dif3(r, tab[g]);
#pragma unroll
        for (int k = 0; k < 8; ++k) cv[swz(g + 1024*k)] = r[k];
    }
    __syncthreads();
    // pass B (stages 9..7)
#pragma unroll 1
    for (int gi = 0; gi < 2; ++gi) {
        int g = t + 512*gi;
        int base = ((g>>7)<<10) | (g&127);
#pragma unroll
        for (int k = 0; k < 8; ++k) r[k] = cv[swz(base + 128*k)];
        dif3(r, wdB);
#pragma unroll
        for (int k = 0; k < 8; ++k) cv[swz(base + 128*k)] = r[k];
    }
    __syncthreads();
    // pass C (stages 6..4)
#pragma unroll 1
    for (int gi = 0; gi < 2; ++gi) {
        int g = t + 512*gi;
        int base = ((g>>4)<<7) | (g&15);
#pragma unroll
        for (int k = 0; k < 8; ++k) r[k] = cv[swz(base + 16*k)];
        dif3(r, wdC);
#pragma unroll
        for (int k = 0; k < 8; ++k) cv[swz(base + 16*k)] = r[k];
    }
    __syncthreads();
    // pass D (stages 3..1)
#pragma unroll 1
    for (int gi = 0; gi < 2; ++gi) {
        int g = t + 512*gi;
        int base = ((g>>1)<<4) | (g&1);
#pragma unroll
        for (int k = 0; k < 8; ++k) r[k] = cv[swz(base + 2*k)];
        dif3(r, wdD);
#pragma unroll
        for (int k = 0; k < 8; ++k) cv[swz(base + 2*k)] = r[k];
    }
    __syncthreads();

    // ---- unpack rfft(K) into registers (q fully unrolled: static Ka/Kb indexing) ----
    float4 Ka[4], Kb[4];
#pragma unroll
    for (int q = 0; q < 4; ++q) {
        int f = t + 512*q;
        if (f == 0) {
            float2 a0,a1; readpair(cv, 0, a0, a1);
            float2 C0 = cadd(a0,a1), C4 = csub(a0,a1);   // fwd stage 0
            const float s = 1.0f/16384.0f;
            Ka[q] = make_float4((C0.x+C0.y)*s + bds, (C0.x-C0.y)*s + bds, C4.x*s + bds, -C4.y*s);
            Kb[q] = make_float4(0.f,0.f,0.f,0.f);
        } else {
            int g = 4096 - f;
            float2 a0,a1,b0,b1;
            readpair(cv, rev13(f), a0, a1);
            readpair(cv, rev13(g), b0, b1);
            float2 Cf=cadd(a0,a1), Cf4=csub(a0,a1), Cg=cadd(b0,b1), Cg4=csub(b0,b1);
            Ka[q] = kpack(Cf, Cg4, getw(T1,T2,f), bds);
            Kb[q] = kpack(Cg, Cf4, getw(T1,T2,g), bds);
        }
    }
    if (t == 0) {
        float2 b0,b1; readpair(cv, 2, b0, b1);   // rev13(2048) = 2
        float4 K20 = kpack(cadd(b0,b1), csub(b0,b1), getw(T1,T2,2048), bds);
        Kex[0] = f2(K20.x, K20.y);
        Kex[1] = f2(K20.z, K20.w);
    }
    __syncthreads();

    // ---- batches ----
#pragma unroll 1
    for (int b = 0; b < 4; ++b) {
        const float2* xr = (const float2*)(x + ((size_t)b*1024 + d)*SEQ_LEN);
        float2* yr = (float2*)(out + ((size_t)b*1024 + d)*SEQ_LEN);

        // F1: pass A from global
#pragma unroll 1
        for (int gi = 0; gi < 2; ++gi) {
            int g = t + 512*gi;
#pragma unroll
            for (int k = 0; k < 4; ++k) r[k] = xr[g + 1024*k];
#pragma unroll
            for (int k = 4; k < 8; ++k) r[k] = f2(0.f,0.f);
            dif3(r, tab[g]);
#pragma unroll
            for (int k = 0; k < 8; ++k) cv[swz(g + 1024*k)] = r[k];
        }
        __syncthreads();
        // F2: pass B
#pragma unroll 1
        for (int gi = 0; gi < 2; ++gi) {
            int g = t + 512*gi;
            int base = ((g>>7)<<10) | (g&127);
#pragma unroll
            for (int k = 0; k < 8; ++k) r[k] = cv[swz(base + 128*k)];
            dif3(r, wdB);
#pragma unroll
            for (int k = 0; k < 8; ++k) cv[swz(base + 128*k)] = r[k];
        }
        __syncthreads();
        // F3: pass C
#pragma unroll 1
        for (int gi = 0; gi < 2; ++gi) {
            int g = t + 512*gi;
            int base = ((g>>4)<<7) | (g&15);
#pragma unroll
            for (int k = 0; k < 8; ++k) r[k] = cv[swz(base + 16*k)];
            dif3(r, wdC);
#pragma unroll
            for (int k = 0; k < 8; ++k) cv[swz(base + 16*k)] = r[k];
        }
        __syncthreads();
        // F4: pass D
#pragma unroll 1
        for (int gi = 0; gi < 2; ++gi) {
            int g = t + 512*gi;
            int base = ((g>>1)<<4) | (g&1);
#pragma unroll
            for (int k = 0; k < 8; ++k) r[k] = cv[swz(base + 2*k)];
            dif3(r, wdD);
#pragma unroll
            for (int k = 0; k < 8; ++k) cv[swz(base + 2*k)] = r[k];
        }
        __syncthreads();

        // FUSED: fwd stage 0 + rfft-unpack * K + repack + inv stage 0 (q unrolled for Ka/Kb)
#pragma unroll
        for (int q = 0; q < 4; ++q) {
            int f = t + 512*q;
            if (f == 0) {
                float2 a0,a1; readpair(cv, 0, a0, a1);
                float2 C0 = cadd(a0,a1), C4 = csub(a0,a1);
                float R0 = C0.x + C0.y, RN = C0.x - C0.y;
                float Y0 = R0 * Ka[0].x, YN = RN * Ka[0].y;
                float2 D0 = f2(Y0+YN, Y0-YN);
                float2 Y4 = cmul(f2(C4.x,-C4.y), f2(Ka[0].z, Ka[0].w));
                float2 D4 = f2(2.f*Y4.x, -2.f*Y4.y);
                writepair(cv, 0, cadd(D0,D4), csub(D0,D4));
            } else {
                int g = 4096 - f;
                int p1 = rev13(f), p2 = rev13(g);
                float2 a0,a1,b0,b1;
                readpair(cv, p1, a0, a1);
                readpair(cv, p2, b0, b1);
                float2 Cf=cadd(a0,a1), Cf4=csub(a0,a1), Cg=cadd(b0,b1), Cg4=csub(b0,b1);
                float2 Df,Dg4,Dg,Df4;
                pwmul(Cf, Cg4, Ka[q], getw(T1,T2,f), Df, Dg4);
                pwmul(Cg, Cf4, Kb[q], getw(T1,T2,g), Dg, Df4);
                writepair(cv, p1, cadd(Df,Df4), csub(Df,Df4));
                writepair(cv, p2, cadd(Dg,Dg4), csub(Dg,Dg4));
            }
        }
        if (t == 0) {   // f = 2048 self-paired quad at positions (2,3)
            float4 K20 = make_float4(Kex[0].x, Kex[0].y, Kex[1].x, Kex[1].y);
            float2 b0,b1; readpair(cv, 2, b0, b1);
            float2 Ck=cadd(b0,b1), Cm=csub(b0,b1), Dk, Dm;
            pwmul(Ck, Cm, K20, getw(T1,T2,2048), Dk, Dm);
            writepair(cv, 2, cadd(Dk,Dm), csub(Dk,Dm));
        }
        __syncthreads();

        // I4: pass D' (stages 1..3)
#pragma unroll 1
        for (int gi = 0; gi < 2; ++gi) {
            int g = t + 512*gi;
            int base = ((g>>1)<<4) | (g&1);
#pragma unroll
            for (int k = 0; k < 8; ++k) r[k] = cv[swz(base + 2*k)];
            dit3(r, wdD);
#pragma unroll
            for (int k = 0; k < 8; ++k) cv[swz(base + 2*k)] = r[k];
        }
        __syncthreads();
        // I3: pass C' (stages 4..6)
#pragma unroll 1
        for (int gi = 0; gi < 2; ++gi) {
            int g = t + 512*gi;
            int base = ((g>>4)<<7) | (g&15);
#pragma unroll
            for (int k = 0; k < 8; ++k) r[k] = cv[swz(base + 16*k)];
            dit3(r, wdC);
#pragma unroll
            for (int k = 0; k < 8; ++k) cv[swz(base + 16*k)] = r[k];
        }
        __syncthreads();
        // I2: pass B' (stages 7..9)
#pragma unroll 1
        for (int gi = 0; gi < 2; ++gi) {
            int g = t + 512*gi;
            int base = ((g>>7)<<10) | (g&127);
#pragma unroll
            for (int k = 0; k < 8; ++k) r[k] = cv[swz(base + 128*k)];
            dit3(r, wdB);
#pragma unroll
            for (int k = 0; k < 8; ++k) cv[swz(base + 128*k)] = r[k];
        }
        __syncthreads();
        // I1: pass A' (stages 10..12), first half straight to global
#pragma unroll 1
        for (int gi = 0; gi < 2; ++gi) {
            int g = t + 512*gi;
#pragma unroll
            for (int k = 0; k < 8; ++k) r[k] = cv[swz(g + 1024*k)];
            dit3(r, tab[g]);
#pragma unroll
            for (int k = 0; k < 4; ++k) yr[g + 1024*k] = r[k];
        }
        __syncthreads();
    }
}

extern "C" void kernel_launch(void* const* d_in, const int* in_sizes, int n_in,
                              void* d_out, int out_size, void* d_ws, size_t ws_size,
                              hipStream_t stream) {
    const float* x    = (const float*)d_in[0];
    const float* z    = (const float*)d_in[2];
    const float* W1   = (const float*)d_in[3];
    const float* b1   = (const float*)d_in[4];
    const float* W2   = (const float*)d_in[5];
    const float* b2   = (const float*)d_in[6];
    const float* W3   = (const float*)d_in[7];
    const float* b3   = (const float*)d_in[8];
    const float* Wout = (const float*)d_in[9];
    const float* freq = (const float*)d_in[10];
    const float* bias = (const float*)d_in[11];
    float* out = (float*)d_out;
    float* h3  = (float*)d_ws;   // 8192*16 floats = 512 KB

    hipLaunchKernelGGL(hyena_mlp, dim3(SEQ_LEN/256), dim3(256), 0, stream,
                       z, W1, b1, W2, b2, W3, b3, freq, h3);

    static bool attr_set = false;
    if (!attr_set) {
        (void)hipFuncSetAttribute((const void*)hyena_conv,
                                  hipFuncAttributeMaxDynamicSharedMemorySize, SMEM_BYTES);
        attr_set = true;
    }
    hipLaunchKernelGGL(hyena_conv, dim3(1024), dim3(NT), SMEM_BYTES, stream,
                       h3, Wout, x, bias, out);
}